// Round 9
// baseline (167.195 us; speedup 1.0000x reference)
//
#include <hip/hip_runtime.h>

// Problem constants (match reference file)
constexpr int   NUM_CLAUSES = 1000000;
constexpr int   NUM_VARS    = 1000000;
constexpr int   NUM_EDGES   = 3000000;   // per polarity
constexpr float Pc = 5.0f;
constexpr float Ac = 10.0f;

// Clause-accumulator packing: low 16 bits = num * 2^6, high 16 = den * 2^6.
// Exactly 3 pos + 3 neg edges per clause; each term <= e^5 = 148.413 ->
// max field sum 6*148.413*64 = 56,990 < 65,536: no overflow, no lo->hi carry.
// Integer adds are order-independent -> bit-identical regardless of schedule.
constexpr float FXSCALE = 64.0f;
constexpr float FXINV   = 1.0f / 64.0f;

// Literal quantization (identical to all previous passing kernels).
constexpr float QSCALE = 1048575.0f;    // 2^20 - 1
constexpr float QINV   = 1.0f / 1048575.0f;

// Bucketing: 500 buckets x 2000 clauses (bucket grid = 2 blocks/CU).
constexpr int NB  = 500;
constexpr int CPB = 2000;               // clauses per bucket (fits 11 bits)

// Partition geometry: 1024 threads, 12288 records per block, 12 per thread.
constexpr int TPB   = 1024;
constexpr int RPB   = 12288;
constexpr int RPT   = RPB / TPB;                     // 12
constexpr int NBLKP = (NUM_EDGES + RPB - 1) / RPB;   // 245 blocks / polarity
constexpr int NBLK  = 2 * NBLKP;                     // 490 total

// Superblock-deterministic placement: 16 partition blocks form a superblock;
// each (superblock, bucket) owns a fixed region of CAPS records.
// lambda = 16*12288/500 = 393.2, sigma ~19.6; CAPS=544 = lambda + 7.6 sigma
// -> overflow P ~1e-9 over all 15,500 regions (fixed dataset; overflow would
// fail the bench loudly). 544*4B = 2176 B = 34 full cache lines (aligned).
constexpr int SBSH = 4;                              // 16 blocks / superblock
constexpr int NSB  = (NBLK + (1 << SBSH) - 1) >> SBSH;   // 31
constexpr int CAPS = 544;

// Record format (u32): variable index (20b) << 12 | polarity (1b) << 11 |
// local clause (11b).
//
// ADDEND TABLE (new this round): the packed fixed-point addend is a pure
// function of (variable, polarity) -- only 2M distinct values for 6M
// records. table_kernel computes tbl[pol*2^20 + v] ONCE via the exact same
// float pipeline (quantize -> dequant -> expf -> pack) -> every record's
// addend is bit-identical to recomputing it inline. The bucket kernel's 6M
// path then does: gather u32 addend + LDS add (4 VALU ops vs ~20).

// Workspace layout (bytes):
//   recs     u32[NSB*NB*CAPS] = 33,728,000  @ 0
//   counters u32[NSB*NB]      =     62,000  @ OFF_CTR   (rank atomics = counts)
//   partials f32[NB]          =      2,000  @ OFF_PAR
//   tbl      u32[2^21]        =  8,388,608  @ OFF_TBL   (pol*2^20 + v)
constexpr size_t OFF_CTR = (size_t)NSB * NB * CAPS * 4;
constexpr size_t OFF_PAR = OFF_CTR + (size_t)NSB * NB * 4;
constexpr size_t OFF_TBL = 33792000;    // 64-aligned, past partials

// Session ledger (counter-verified):
//  - NT record re-reads:  +33 us (R5, exposed HBM latency)       -> cached.
//  - __threadfence/block: +30 us (R6, per-block L2 invalidate)   -> separate
//    final kernel; kernel boundary is the fence.
//  - NT adjacency loads:  +8 us  (R7 vs R4 single-diff)          -> cached.
//  - bucket 2-run ILP pairing: neutral (R8)                      -> kept.

__device__ __forceinline__ unsigned pack_fx(float num, float den) {
    unsigned lo = (unsigned)(num * FXSCALE + 0.5f);
    unsigned hi = (unsigned)(den * FXSCALE + 0.5f);
    return lo | (hi << 16);
}

// ---------------------------------------------------------------------------
// Addend table: one thread per variable computes both polarity entries with
// the EXACT per-record float pipeline used by all previous passing rounds.
// ---------------------------------------------------------------------------
__global__ __launch_bounds__(256)
void table_kernel(const float* __restrict__ x, unsigned* __restrict__ tbl) {
    int v = (int)(blockIdx.x * 256 + threadIdx.x);
    if (v < NUM_VARS) {
        float xv = x[v];
        {   // positive polarity: lit = x
            float    lit = xv;
            unsigned q   = (unsigned)(lit * QSCALE + 0.5f);
            float    lq  = (float)q * QINV;
            float    w   = __expf(Pc * lq);
            tbl[v] = pack_fx(lq * w, w);
        }
        {   // negative polarity: lit = 1 - x
            float    lit = 1.0f - xv;
            unsigned q   = (unsigned)(lit * QSCALE + 0.5f);
            float    lq  = (float)q * QINV;
            float    w   = __expf(Pc * lq);
            tbl[(1u << 20) + (unsigned)v] = pack_fx(lq * w, w);
        }
    }
}

// ---------------------------------------------------------------------------
// Partition BOTH polarities' 6M edge records into NB clause-range buckets.
// (Exactly the R4 kernel -- best measured partition.)
// ---------------------------------------------------------------------------
__global__ __launch_bounds__(TPB)
void partition_kernel(const int*   __restrict__ adj_pos,
                      const int*   __restrict__ adj_neg,
                      unsigned* __restrict__ recs,
                      unsigned* __restrict__ counters) {
    // hist_sbase: per-bucket histogram, then re-used (same element, same
    // owning thread, barrier-fenced) as the combined global base.
    __shared__ unsigned       hist_sbase[NB];
    __shared__ unsigned       lbase[NB];    // block-local exclusive scan
    __shared__ unsigned       srec[RPB];    // 48 KB staging, bucket-sorted
    __shared__ unsigned short sbid[RPB];    // 24 KB bucket id per staged slot
    __shared__ unsigned       wsum[TPB / 64];
    __shared__ unsigned       woff[TPB / 64];

    const bool neg   = (blockIdx.x >= (unsigned)NBLKP);
    const int  sblk  = neg ? (int)blockIdx.x - NBLKP : (int)blockIdx.x;
    const int  sb    = (int)blockIdx.x >> SBSH;      // superblock id
    const int  start = sblk * RPB;
    const int  n     = min(RPB, NUM_EDGES - start);
    const int* crow  = neg ? adj_neg : adj_pos;
    const int* vrow  = crow + NUM_EDGES;
    const int  tid   = (int)threadIdx.x;
    const unsigned polbit = neg ? 0x800u : 0u;

    if (tid < NB) hist_sbase[tid] = 0;
    __syncthreads();

    // ---- load adjacency (vectorized int4, coalesced, CACHED) ----
    int cc_[RPT], vv_[RPT];
    if (n == RPB) {
        #pragma unroll
        for (int j = 0; j < RPT / 4; ++j) {
            int4 c4 = ((const int4*)(crow + start))[j * TPB + tid];
            cc_[4*j] = c4.x; cc_[4*j+1] = c4.y; cc_[4*j+2] = c4.z; cc_[4*j+3] = c4.w;
        }
        #pragma unroll
        for (int j = 0; j < RPT / 4; ++j) {
            int4 v4 = ((const int4*)(vrow + start))[j * TPB + tid];
            vv_[4*j] = v4.x; vv_[4*j+1] = v4.y; vv_[4*j+2] = v4.z; vv_[4*j+3] = v4.w;
        }
    } else {
        #pragma unroll
        for (int r = 0; r < RPT; ++r) {
            int pos = 4 * ((r >> 2) * TPB + tid) + (r & 3);
            cc_[r] = (pos < n) ? crow[start + pos] : -1;
            vv_[r] = (pos < n) ? vrow[start + pos] : 0;
        }
    }

    // ---- hist-rank atomics (clause ids only) ----
    unsigned meta[RPT];   // meta = b<<14 | rank (valid only where cc_>=0)
    #pragma unroll
    for (int r = 0; r < RPT; ++r) {
        meta[r] = 0;
        if (cc_[r] >= 0) {
            int b = cc_[r] / CPB;
            unsigned rank = atomicAdd(&hist_sbase[b], 1u);
            meta[r] = ((unsigned)b << 14) | rank;
        }
    }
    __syncthreads();

    // ---- block-local exclusive scan of hist (wave shuffles) ----
    unsigned h    = (tid < NB) ? hist_sbase[tid] : 0u;
    unsigned incl = h;
    #pragma unroll
    for (int off = 1; off < 64; off <<= 1) {
        unsigned t = __shfl_up(incl, off, 64);
        if ((tid & 63) >= off) incl += t;
    }
    if ((tid & 63) == 63) wsum[tid >> 6] = incl;
    __syncthreads();
    if (tid == 0) {
        unsigned a = 0;
        #pragma unroll
        for (int w = 0; w < TPB / 64; ++w) { woff[w] = a; a += wsum[w]; }
    }
    __syncthreads();
    if (tid < NB) lbase[tid] = incl - h + woff[tid >> 6];
    __syncthreads();

    // ---- reservation atomic on the 16-way superblock counter (staggered).
    //      Result consumed only AFTER staging -> latency overlapped.
    unsigned gbase = 0;
    int      rb    = 0;
    if (tid < NB) {
        rb = tid + (int)blockIdx.x;            // blockIdx < 490 < 2*NB
        if (rb >= NB) rb -= NB;
        unsigned hr   = hist_sbase[rb];
        unsigned base = (unsigned)(sb * NB + rb) * (unsigned)CAPS;
        gbase = base + (hr ? atomicAdd(&counters[sb * NB + rb], hr) : 0u);
    }

    // ---- build records (pure ALU) + stage bucket-sorted into LDS ----
    #pragma unroll
    for (int r = 0; r < RPT; ++r) {
        if (cc_[r] >= 0) {
            unsigned b    = meta[r] >> 14;
            unsigned rank = meta[r] & 0x3FFFu;
            unsigned loc  = (unsigned)(cc_[r] - (int)b * CPB);
            unsigned p    = lbase[b] + rank;
            srec[p] = ((unsigned)vv_[r] << 12) | polbit | loc;
            sbid[p] = (unsigned short)b;
        }
    }
    if (tid < NB) hist_sbase[rb] = gbase;   // reservation return lands here
    __syncthreads();

    // ---- coalesced writeout (consecutive p -> consecutive global) ----
    for (int p = tid; p < n; p += TPB) {
        unsigned b = sbid[p];
        recs[hist_sbase[b] + ((unsigned)p - lbase[b])] = srec[p];
    }
}

// ---------------------------------------------------------------------------
// Bucket phase: one block per bucket (500 blocks -> 2/CU, 32 waves).
// Each wave processes two runs in lockstep (R8 structure). Per record the
// work is now: idx = v | pol<<20 -> gather u32 addend from tbl -> guarded
// LDS add. All 8 gathers issued before any use. No clamps needed: idx is
// always < 2^21 (table covers the full 20b+pol space); garbage addends on
// dummy/tail lanes are discarded by the rem guards.
// Integer LDS accumulation is order-independent -> bit-identical result.
// ---------------------------------------------------------------------------
__global__ __launch_bounds__(1024)
void bucket_loss_kernel(const unsigned* __restrict__ recs,
                        const unsigned* __restrict__ counters,
                        const unsigned* __restrict__ tbl,
                        const float* __restrict__ cc,
                        float* __restrict__ partials) {
    __shared__ unsigned lacc[CPB];   // 8 KB
    const int b    = blockIdx.x;
    const int tid  = (int)threadIdx.x;
    const int lane = tid & 63;
    const int wid  = tid >> 6;
    for (int j = tid; j < CPB; j += 1024) lacc[j] = 0;
    __syncthreads();

    // Wave wid owns runs s1=wid and s2=wid+16 (wave 15 takes run 15 alone).
    const int s1 = wid;
    const int s2 = wid + 16;
    const bool has2 = (s2 < NSB);

    const unsigned idx1 = (unsigned)(s1 * NB + b);
    const unsigned idx2 = has2 ? (unsigned)(s2 * NB + b) : idx1;
    const unsigned cnt1 = counters[idx1];
    const unsigned cnt2 = has2 ? counters[idx2] : 0u;
    const uint4* rr1 = (const uint4*)(recs + (size_t)idx1 * CAPS);
    const uint4* rr2 = (const uint4*)(recs + (size_t)idx2 * CAPS);
    const int nq1 = (int)((cnt1 + 3u) >> 2);
    const int nq2 = (int)((cnt2 + 3u) >> 2);
    const int nmx = max(nq1, nq2);

    for (int i = lane; i < nmx; i += 64) {
        const bool a1 = i < nq1;
        const bool a2 = i < nq2;
        // Both quad loads issued together (index 0 is always-valid dummy).
        uint4 e1 = rr1[a1 ? i : 0];
        uint4 e2 = rr2[a2 ? i : 0];
        // tbl index: v | pol<<20  (== (rv>>12) | ((rv&0x800)<<9)).
        unsigned t10 = tbl[(e1.x >> 12) | ((e1.x & 0x800u) << 9)];
        unsigned t11 = tbl[(e1.y >> 12) | ((e1.y & 0x800u) << 9)];
        unsigned t12 = tbl[(e1.z >> 12) | ((e1.z & 0x800u) << 9)];
        unsigned t13 = tbl[(e1.w >> 12) | ((e1.w & 0x800u) << 9)];
        unsigned t20 = tbl[(e2.x >> 12) | ((e2.x & 0x800u) << 9)];
        unsigned t21 = tbl[(e2.y >> 12) | ((e2.y & 0x800u) << 9)];
        unsigned t22 = tbl[(e2.z >> 12) | ((e2.z & 0x800u) << 9)];
        unsigned t23 = tbl[(e2.w >> 12) | ((e2.w & 0x800u) << 9)];
        const int rem1 = (int)cnt1 - (i << 2);
        const int rem2 = (int)cnt2 - (i << 2);

        if (rem1 > 0) atomicAdd(&lacc[e1.x & 0x7FFu], t10);
        if (rem1 > 1) atomicAdd(&lacc[e1.y & 0x7FFu], t11);
        if (rem1 > 2) atomicAdd(&lacc[e1.z & 0x7FFu], t12);
        if (rem1 > 3) atomicAdd(&lacc[e1.w & 0x7FFu], t13);
        if (rem2 > 0) atomicAdd(&lacc[e2.x & 0x7FFu], t20);
        if (rem2 > 1) atomicAdd(&lacc[e2.y & 0x7FFu], t21);
        if (rem2 > 2) atomicAdd(&lacc[e2.z & 0x7FFu], t22);
        if (rem2 > 3) atomicAdd(&lacc[e2.w & 0x7FFu], t23);
    }
    __syncthreads();

    float v = 0.0f;
    const float* gc = cc + (size_t)b * CPB;
    for (int j = tid; j < CPB; j += 1024) {
        unsigned a   = lacc[j];                 // packed fields can't overflow
        float    num = (float)(a & 0xffffu) * FXINV;
        float    den = (float)(a >> 16)     * FXINV;
        float    sm  = 1.0f / (1.0f + __expf(-Ac * (num / den - 0.5f)));
        float    e0f = sm - gc[j];
        v += e0f * e0f;
    }
    v *= 1.0f / (float)NUM_CLAUSES;

    #pragma unroll
    for (int off = 32; off > 0; off >>= 1)
        v += __shfl_down(v, off, 64);

    __shared__ float partial[16];   // 1024 threads = 16 waves
    if (lane == 0) partial[wid] = v;
    __syncthreads();
    if (tid == 0) {
        float s = 0.f;
        #pragma unroll
        for (int w = 0; w < 16; ++w) s += partial[w];
        partials[b] = s;
    }
}

// ---------------------------------------------------------------------------
// Final reduce: ONE block sums NB partials, plain-stores out[0].
// Kernel boundary provides the cross-block ordering (no device fences).
// ---------------------------------------------------------------------------
__global__ void final_kernel(const float* __restrict__ partials,
                             float* __restrict__ out, int n) {
    float v = 0.0f;
    for (int i = threadIdx.x; i < n; i += 256) v += partials[i];

    #pragma unroll
    for (int off = 32; off > 0; off >>= 1)
        v += __shfl_down(v, off, 64);

    __shared__ float partial[4];
    int lane = threadIdx.x & 63;
    int wid  = threadIdx.x >> 6;
    if (lane == 0) partial[wid] = v;
    __syncthreads();
    if (threadIdx.x == 0)
        out[0] = partial[0] + partial[1] + partial[2] + partial[3];
}

// ---------------------------------------------------------------------------
extern "C" void kernel_launch(void* const* d_in, const int* in_sizes, int n_in,
                              void* d_out, int out_size, void* d_ws, size_t ws_size,
                              hipStream_t stream) {
    const float* xv      = (const float*)d_in[0];   // [V] fp32
    const int*   adj_pos = (const int*)  d_in[1];   // [2,E] int32
    const int*   adj_neg = (const int*)  d_in[2];   // [2,E] int32
    const float* cc      = (const float*)d_in[3];   // [C] fp32 (ones)

    char* ws = (char*)d_ws;
    unsigned* recs     = (unsigned*)ws;
    unsigned* counters = (unsigned*)(ws + OFF_CTR);
    float*    partials = (float*)   (ws + OFF_PAR);
    unsigned* tbl      = (unsigned*)(ws + OFF_TBL);
    float*    out      = (float*)d_out;

    // 1) zero the superblock rank counters (62 KB)
    hipMemsetAsync(counters, 0, (size_t)NSB * NB * sizeof(unsigned), stream);

    // 2) per-(variable,polarity) packed addend table (exact float pipeline)
    table_kernel<<<(NUM_VARS + 255) / 256, 256, 0, stream>>>(xv, tbl);

    // 3) partition both polarities into (superblock,bucket) record runs
    partition_kernel<<<NBLK, TPB, 0, stream>>>(adj_pos, adj_neg,
                                               recs, counters);

    // 4) per-bucket table-gather + LDS accumulate + loss -> partial/bucket
    bucket_loss_kernel<<<NB, 1024, 0, stream>>>(recs, counters, tbl, cc,
                                                partials);

    // 5) single-block final reduce -> out[0]
    final_kernel<<<1, 256, 0, stream>>>(partials, out, NB);
}

// Round 10
// 137.837 us; speedup vs baseline: 1.2130x; 1.2130x over previous
//
#include <hip/hip_runtime.h>

// Problem constants (match reference file)
constexpr int   NUM_CLAUSES = 1000000;
constexpr int   NUM_EDGES   = 3000000;   // per polarity
constexpr float Pc = 5.0f;
constexpr float Ac = 10.0f;

// Clause-accumulator packing: low 16 bits = num * 2^6, high 16 = den * 2^6.
// Exactly 3 pos + 3 neg edges per clause; each term <= e^5 = 148.413 ->
// max field sum 6*148.413*64 = 56,990 < 65,536: no overflow, no lo->hi carry.
// Integer adds are order-independent -> bit-identical regardless of schedule.
constexpr float FXSCALE = 64.0f;
constexpr float FXINV   = 1.0f / 64.0f;

// Literal quantization (identical to all previous passing kernels).
constexpr float QSCALE = 1048575.0f;    // 2^20 - 1
constexpr float QINV   = 1.0f / 1048575.0f;

// Bucketing: 500 buckets x 2000 clauses (bucket grid = 2 blocks/CU).
constexpr int NB  = 500;
constexpr int CPB = 2000;               // clauses per bucket (fits 11 bits)

// Partition geometry: 1024 threads, 12288 records per block, 12 per thread.
constexpr int TPB   = 1024;
constexpr int RPB   = 12288;
constexpr int RPT   = RPB / TPB;                     // 12
constexpr int NBLKP = (NUM_EDGES + RPB - 1) / RPB;   // 245 blocks / polarity
constexpr int NBLK  = 2 * NBLKP;                     // 490 total

// Superblock-deterministic placement: 16 partition blocks form a superblock;
// each (superblock, bucket) owns a fixed region of CAPS records.
// lambda = 16*12288/500 = 393.2, sigma ~19.6; CAPS=544 = lambda + 7.6 sigma
// -> overflow P ~1e-9 over all 15,500 regions (fixed dataset; overflow would
// fail the bench loudly). 544*4B = 2176 B = 34 full cache lines (aligned).
constexpr int SBSH = 4;                              // 16 blocks / superblock
constexpr int NSB  = (NBLK + (1 << SBSH) - 1) >> SBSH;   // 31
constexpr int CAPS = 544;

// Record format (u32): variable index (20b) << 12 | polarity (1b) << 11 |
// local clause (11b). Bucket kernel gathers x and reproduces the exact
// quantize->pack pipeline (bit-identical numerics).

// Workspace layout (bytes):
//   recs     u32[NSB*NB*CAPS] = 33,728,000  @ 0
//   counters u32[NSB*NB]      =     62,000  @ OFF_CTR   (rank atomics = counts)
//   partials f32[NB]          @ OFF_PAR
constexpr size_t OFF_CTR = (size_t)NSB * NB * CAPS * 4;
constexpr size_t OFF_PAR = OFF_CTR + (size_t)NSB * NB * 4;

// Session ledger (counter-verified; R4 config = empirical optimum 137.8 us):
//  - global atomic scatter:   +100 us (R3, 25 atomics/ns, 32B/atomic HBM RMW)
//  - NT record re-reads:      +33 us  (R5, exposed HBM latency)
//  - __threadfence per block: +30 us  (R6, per-block L2 writeback/invalidate)
//  - NT adjacency loads:      +8 us   (R7 vs R4 single-diff)
//  - bucket 2-run ILP pairing: neutral (R8) -> phase is not VALU/ILP-bound
//  - 8 MB addend table:       +29 us  (R9, FETCH 213 MB: gather working set
//    must fit the 4 MB per-XCD L2; recompute beats bigger-gather)

__device__ __forceinline__ unsigned pack_fx(float num, float den) {
    unsigned lo = (unsigned)(num * FXSCALE + 0.5f);
    unsigned hi = (unsigned)(den * FXSCALE + 0.5f);
    return lo | (hi << 16);
}

// ---------------------------------------------------------------------------
// Partition BOTH polarities' 6M edge records into NB clause-range buckets.
// Grid = 2*NBLKP: first half reads adj_pos, second half adj_neg.
// No gathers (records carry the variable index). Reservation targets the
// per-(superblock,bucket) counter -> 16-way contention; region base is
// deterministic: gbase = (sb*NB+b)*CAPS + rank.  (Exactly the R4 kernel.)
// ---------------------------------------------------------------------------
__global__ __launch_bounds__(TPB)
void partition_kernel(const int*   __restrict__ adj_pos,
                      const int*   __restrict__ adj_neg,
                      unsigned* __restrict__ recs,
                      unsigned* __restrict__ counters) {
    // hist_sbase: per-bucket histogram, then re-used (same element, same
    // owning thread, barrier-fenced) as the combined global base.
    __shared__ unsigned       hist_sbase[NB];
    __shared__ unsigned       lbase[NB];    // block-local exclusive scan
    __shared__ unsigned       srec[RPB];    // 48 KB staging, bucket-sorted
    __shared__ unsigned short sbid[RPB];    // 24 KB bucket id per staged slot
    __shared__ unsigned       wsum[TPB / 64];
    __shared__ unsigned       woff[TPB / 64];

    const bool neg   = (blockIdx.x >= (unsigned)NBLKP);
    const int  sblk  = neg ? (int)blockIdx.x - NBLKP : (int)blockIdx.x;
    const int  sb    = (int)blockIdx.x >> SBSH;      // superblock id
    const int  start = sblk * RPB;
    const int  n     = min(RPB, NUM_EDGES - start);
    const int* crow  = neg ? adj_neg : adj_pos;
    const int* vrow  = crow + NUM_EDGES;
    const int  tid   = (int)threadIdx.x;
    const unsigned polbit = neg ? 0x800u : 0u;

    if (tid < NB) hist_sbase[tid] = 0;
    __syncthreads();

    // ---- load adjacency (vectorized int4, coalesced, CACHED) ----
    int cc_[RPT], vv_[RPT];
    if (n == RPB) {
        #pragma unroll
        for (int j = 0; j < RPT / 4; ++j) {
            int4 c4 = ((const int4*)(crow + start))[j * TPB + tid];
            cc_[4*j] = c4.x; cc_[4*j+1] = c4.y; cc_[4*j+2] = c4.z; cc_[4*j+3] = c4.w;
        }
        #pragma unroll
        for (int j = 0; j < RPT / 4; ++j) {
            int4 v4 = ((const int4*)(vrow + start))[j * TPB + tid];
            vv_[4*j] = v4.x; vv_[4*j+1] = v4.y; vv_[4*j+2] = v4.z; vv_[4*j+3] = v4.w;
        }
    } else {
        #pragma unroll
        for (int r = 0; r < RPT; ++r) {
            int pos = 4 * ((r >> 2) * TPB + tid) + (r & 3);
            cc_[r] = (pos < n) ? crow[start + pos] : -1;
            vv_[r] = (pos < n) ? vrow[start + pos] : 0;
        }
    }

    // ---- hist-rank atomics (clause ids only) ----
    unsigned meta[RPT];   // meta = b<<14 | rank (valid only where cc_>=0)
    #pragma unroll
    for (int r = 0; r < RPT; ++r) {
        meta[r] = 0;
        if (cc_[r] >= 0) {
            int b = cc_[r] / CPB;
            unsigned rank = atomicAdd(&hist_sbase[b], 1u);
            meta[r] = ((unsigned)b << 14) | rank;
        }
    }
    __syncthreads();

    // ---- block-local exclusive scan of hist (wave shuffles) ----
    unsigned h    = (tid < NB) ? hist_sbase[tid] : 0u;
    unsigned incl = h;
    #pragma unroll
    for (int off = 1; off < 64; off <<= 1) {
        unsigned t = __shfl_up(incl, off, 64);
        if ((tid & 63) >= off) incl += t;
    }
    if ((tid & 63) == 63) wsum[tid >> 6] = incl;
    __syncthreads();
    if (tid == 0) {
        unsigned a = 0;
        #pragma unroll
        for (int w = 0; w < TPB / 64; ++w) { woff[w] = a; a += wsum[w]; }
    }
    __syncthreads();
    if (tid < NB) lbase[tid] = incl - h + woff[tid >> 6];
    __syncthreads();

    // ---- reservation atomic on the 16-way superblock counter (staggered).
    //      Result consumed only AFTER staging -> latency overlapped.
    unsigned gbase = 0;
    int      rb    = 0;
    if (tid < NB) {
        rb = tid + (int)blockIdx.x;            // blockIdx < 490 < 2*NB
        if (rb >= NB) rb -= NB;
        unsigned hr   = hist_sbase[rb];
        unsigned base = (unsigned)(sb * NB + rb) * (unsigned)CAPS;
        gbase = base + (hr ? atomicAdd(&counters[sb * NB + rb], hr) : 0u);
    }

    // ---- build records (pure ALU) + stage bucket-sorted into LDS ----
    #pragma unroll
    for (int r = 0; r < RPT; ++r) {
        if (cc_[r] >= 0) {
            unsigned b    = meta[r] >> 14;
            unsigned rank = meta[r] & 0x3FFFu;
            unsigned loc  = (unsigned)(cc_[r] - (int)b * CPB);
            unsigned p    = lbase[b] + rank;
            srec[p] = ((unsigned)vv_[r] << 12) | polbit | loc;
            sbid[p] = (unsigned short)b;
        }
    }
    if (tid < NB) hist_sbase[rb] = gbase;   // reservation return lands here
    __syncthreads();

    // ---- coalesced writeout (consecutive p -> consecutive global) ----
    for (int p = tid; p < n; p += TPB) {
        unsigned b = sbid[p];
        recs[hist_sbase[b] + ((unsigned)p - lbase[b])] = srec[p];
    }
}

// ---------------------------------------------------------------------------
// Bucket phase: one block per bucket (500 blocks -> 2/CU, 32 waves).
// Reads the bucket's 31 superblock runs (avg 393 records, dense) with
// CACHED uint4 loads. Gather x (4 MB, fits per-XCD L2) per record, exp,
// LDS-atomic the packed term, then sigmoid + squared error + reduce
// (byte-identical float order to all previous passing rounds).
// No device fences anywhere in this kernel.  (Exactly the R4 kernel.)
// ---------------------------------------------------------------------------
__global__ __launch_bounds__(1024)
void bucket_loss_kernel(const unsigned* __restrict__ recs,
                        const unsigned* __restrict__ counters,
                        const float* __restrict__ x,
                        const float* __restrict__ cc,
                        float* __restrict__ partials) {
    __shared__ unsigned lacc[CPB];   // 8 KB
    const int b    = blockIdx.x;
    const int tid  = (int)threadIdx.x;
    const int lane = tid & 63;
    const int wid  = tid >> 6;
    for (int j = tid; j < CPB; j += 1024) lacc[j] = 0;
    __syncthreads();

    // 16 waves round-robin the 31 superblock runs of this bucket.
    for (int s = wid; s < NSB; s += 16) {
        const unsigned idx = (unsigned)(s * NB + b);
        const unsigned cnt = counters[idx];              // wave-uniform
        const uint4*   rr  = (const uint4*)(recs + (size_t)idx * CAPS);
        const int      nq  = (int)((cnt + 3u) >> 2);
        for (int i = lane; i < nq; i += 64) {
            uint4 e   = rr[i];
            int   rem = (int)cnt - (i << 2);             // >= 1 here
            #define PROC(r, act)                                           \
                do { if (act) {                                            \
                    unsigned rv  = (r);                                    \
                    float    xv  = x[rv >> 12];                            \
                    float    lit = (rv & 0x800u) ? (1.0f - xv) : xv;       \
                    unsigned q   = (unsigned)(lit * QSCALE + 0.5f);        \
                    float    lq  = (float)q * QINV;                        \
                    float    w   = __expf(Pc * lq);                        \
                    atomicAdd(&lacc[rv & 0x7FFu], pack_fx(lq * w, w));     \
                } } while (0)
            PROC(e.x, true);
            PROC(e.y, rem > 1);
            PROC(e.z, rem > 2);
            PROC(e.w, rem > 3);
            #undef PROC
        }
    }
    __syncthreads();

    float v = 0.0f;
    const float* gc = cc + (size_t)b * CPB;
    for (int j = tid; j < CPB; j += 1024) {
        unsigned a   = lacc[j];                 // packed fields can't overflow
        float    num = (float)(a & 0xffffu) * FXINV;
        float    den = (float)(a >> 16)     * FXINV;
        float    sm  = 1.0f / (1.0f + __expf(-Ac * (num / den - 0.5f)));
        float    e0f = sm - gc[j];
        v += e0f * e0f;
    }
    v *= 1.0f / (float)NUM_CLAUSES;

    #pragma unroll
    for (int off = 32; off > 0; off >>= 1)
        v += __shfl_down(v, off, 64);

    __shared__ float partial[16];   // 1024 threads = 16 waves
    if (lane == 0) partial[wid] = v;
    __syncthreads();
    if (tid == 0) {
        float s = 0.f;
        #pragma unroll
        for (int w = 0; w < 16; ++w) s += partial[w];
        partials[b] = s;
    }
}

// ---------------------------------------------------------------------------
// Final reduce: ONE block sums NB partials, plain-stores out[0].
// Kernel boundary provides the cross-block ordering (no device fences).
// ---------------------------------------------------------------------------
__global__ void final_kernel(const float* __restrict__ partials,
                             float* __restrict__ out, int n) {
    float v = 0.0f;
    for (int i = threadIdx.x; i < n; i += 256) v += partials[i];

    #pragma unroll
    for (int off = 32; off > 0; off >>= 1)
        v += __shfl_down(v, off, 64);

    __shared__ float partial[4];
    int lane = threadIdx.x & 63;
    int wid  = threadIdx.x >> 6;
    if (lane == 0) partial[wid] = v;
    __syncthreads();
    if (threadIdx.x == 0)
        out[0] = partial[0] + partial[1] + partial[2] + partial[3];
}

// ---------------------------------------------------------------------------
extern "C" void kernel_launch(void* const* d_in, const int* in_sizes, int n_in,
                              void* d_out, int out_size, void* d_ws, size_t ws_size,
                              hipStream_t stream) {
    const float* xv      = (const float*)d_in[0];   // [V] fp32
    const int*   adj_pos = (const int*)  d_in[1];   // [2,E] int32
    const int*   adj_neg = (const int*)  d_in[2];   // [2,E] int32
    const float* cc      = (const float*)d_in[3];   // [C] fp32 (ones)

    char* ws = (char*)d_ws;
    unsigned* recs     = (unsigned*)ws;
    unsigned* counters = (unsigned*)(ws + OFF_CTR);
    float*    partials = (float*)   (ws + OFF_PAR);
    float*    out      = (float*)d_out;

    // 1) zero the superblock rank counters (62 KB)
    hipMemsetAsync(counters, 0, (size_t)NSB * NB * sizeof(unsigned), stream);

    // 2) partition both polarities into (superblock,bucket) record runs
    partition_kernel<<<NBLK, TPB, 0, stream>>>(adj_pos, adj_neg,
                                               recs, counters);

    // 3) per-bucket gather + LDS accumulate + loss -> one partial per bucket
    bucket_loss_kernel<<<NB, 1024, 0, stream>>>(recs, counters, xv, cc,
                                                partials);

    // 4) single-block final reduce -> out[0]
    final_kernel<<<1, 256, 0, stream>>>(partials, out, NB);
}